// Round 11
// baseline (1468.635 us; speedup 1.0000x reference)
//
#include <hip/hip_runtime.h>
#include <hip/hip_fp16.h>

#define B_  256
#define T_  512
#define I_  64
#define H_  128
#define G_  384
#define HC  256

// Workspace layout (stream-ordered aliasing: x16 occupies the head of the xw1
// region — gemm overwrites it only after scan_l0 has fully consumed x16).
#define O_OUT0 0ull                    // fp16 [B][T][2H] = 67,108,864
#define O_XW1  67108864ull             // fp16 [B][T][3H] = 100,663,296 (xw1; x16 aliases head)
#define O_X16  O_XW1                   // fp16 [B][T][64] = 16,777,216 (until gemm runs)
#define O_WP   167772160ull            // packed half2 Wih1b, 196,608
#define O_H1F  (O_WP + 196608ull)      // f32 [B][H] = 131,072
#define O_WF16 (O_H1F + 131072ull)     // fp16 Wih1f [384][256] = 196,608

typedef _Float16 h8 __attribute__((ext_vector_type(8)));
typedef _Float16 h2 __attribute__((ext_vector_type(2)));
typedef float    f4 __attribute__((ext_vector_type(4)));

__device__ __forceinline__ float sigm(float x)   { return __builtin_amdgcn_rcpf(1.f + __expf(-x)); }
__device__ __forceinline__ float tanh_f(float x) { return 1.f - 2.f * __builtin_amdgcn_rcpf(1.f + __expf(2.f * x)); }

// LDS-only barrier: waits lgkmcnt(0) but NOT vmcnt.
__device__ __forceinline__ void bar_lds() {
    asm volatile("s_waitcnt lgkmcnt(0)\n\ts_barrier" ::: "memory");
}

__device__ __forceinline__ h8 load_w8(const float* src) {
    f4 a = *(const f4*)src;
    f4 b = *(const f4*)(src + 4);
    h8 v;
    v[0]=(_Float16)a[0]; v[1]=(_Float16)a[1]; v[2]=(_Float16)a[2]; v[3]=(_Float16)a[3];
    v[4]=(_Float16)b[0]; v[5]=(_Float16)b[1]; v[6]=(_Float16)b[2]; v[7]=(_Float16)b[3];
    return v;
}

// Fused prep: x->fp16 (4096 blocks), Wih1f->fp16 (48), Wih1b pack-T (192).
__global__ void prep(const float* __restrict__ x, _Float16* __restrict__ x16,
                     const float* __restrict__ Wf, _Float16* __restrict__ wf16,
                     const float* __restrict__ W1b, __half2* __restrict__ wp) {
    const int bid = blockIdx.x;
    const int tid = threadIdx.x;
    if (bid < 4096) {
        int i = bid * 256 + tid;
        const float* s = x + (size_t)i * 8;
        f4 a = *(const f4*)s, b = *(const f4*)(s + 4);
        h8 v;
        v[0]=(_Float16)a[0]; v[1]=(_Float16)a[1]; v[2]=(_Float16)a[2]; v[3]=(_Float16)a[3];
        v[4]=(_Float16)b[0]; v[5]=(_Float16)b[1]; v[6]=(_Float16)b[2]; v[7]=(_Float16)b[3];
        *(h8*)(x16 + (size_t)i * 8) = v;
    } else if (bid < 4144) {
        int i = (bid - 4096) * 256 + tid;
        const float* s = Wf + (size_t)i * 8;
        f4 a = *(const f4*)s, b = *(const f4*)(s + 4);
        h8 v;
        v[0]=(_Float16)a[0]; v[1]=(_Float16)a[1]; v[2]=(_Float16)a[2]; v[3]=(_Float16)a[3];
        v[4]=(_Float16)b[0]; v[5]=(_Float16)b[1]; v[6]=(_Float16)b[2]; v[7]=(_Float16)b[3];
        *(h8*)(wf16 + (size_t)i * 8) = v;
    } else {
        int i = (bid - 4144) * 256 + tid;
        int c = i % G_;
        int k2 = i / G_;
        wp[i] = __halves2half2(__float2half(W1b[c * 256 + 2 * k2]),
                               __float2half(W1b[c * 256 + 2 * k2 + 1]));
    }
}

// ---------------- Layer-0 scan: wave-specialized, TWO independent 16-row groups ----------------
// 32 batch rows/block (2 groups), 8 blocks x 2 dirs. Weights shared across groups.
// Group B's MFMAs issue while group A's chain drains; A's gates overlap B's MFMAs.
__launch_bounds__(768, 1)
__global__ void scan_l0(const _Float16* __restrict__ x16,
                        const float* __restrict__ Wih_f, const float* __restrict__ Whh_f,
                        const float* __restrict__ bih_f, const float* __restrict__ bhh_f,
                        const float* __restrict__ Wih_b, const float* __restrict__ Whh_b,
                        const float* __restrict__ bih_b, const float* __restrict__ bhh_b,
                        _Float16* __restrict__ out0) {
    __shared__ __align__(16) _Float16 s_h[2][2][16 * 128];   // [buf][grp], 16 KB
    __shared__ __align__(16) _Float16 s_x[2][2][16 * 64];    // [buf][grp], 8 KB

    const int tid  = threadIdx.x;
    const int lane = tid & 63;
    const int w    = tid >> 6;
    const int dir  = blockIdx.y;
    const int b0   = blockIdx.x * 32;

    const float* Wih = dir ? Wih_b : Wih_f;
    const float* Whh = dir ? Whh_b : Whh_f;
    const float* bih = dir ? bih_b : bih_f;
    const float* bhh = dir ? bhh_b : bhh_f;

    {   // prologue: zero h buf0 (both groups); producers stage x(tt(0)) both groups
        _Float16* ph = &s_h[0][0][0];
        for (int i = tid; i < 2 * 16 * 128; i += 768) ph[i] = (_Float16)0.f;
        if (w >= 8) {
            int pt = tid - 512;                 // 0..255: 32 rows x 8 granules
            int xr = pt >> 3, xg = pt & 7;
            int grp = xr >> 4, r16 = xr & 15;
            int t0 = dir ? (T_ - 1) : 0;
            h8 v = *(const h8*)(x16 + ((size_t)(b0 + xr) * T_ + t0) * I_ + xg * 8);
            *(h8*)&s_x[0][grp][r16 * 64 + ((xg ^ (r16 & 7)) & 7) * 8] = v;
        }
    }
    __syncthreads();

    if (w < 8) {   // ================= COMPUTE =================
        const int ln15 = lane & 15;
        const int lq   = lane >> 4;
        const int col  = 16 * w + ln15;
        h8 bh[3][4], bx[3][2];
        float seedR = bih[col] + bhh[col];
        float seedZ = bih[H_ + col] + bhh[H_ + col];
        float bihN  = bih[2 * H_ + col];
        float bhhN  = bhh[2 * H_ + col];
#pragma unroll
        for (int g = 0; g < 3; g++) {
            int n = g * H_ + col;
#pragma unroll
            for (int kt = 0; kt < 4; kt++) bh[g][kt] = load_w8(Whh + (size_t)n * H_ + kt * 32 + lq * 8);
#pragma unroll
            for (int kt = 0; kt < 2; kt++) bx[g][kt] = load_w8(Wih + (size_t)n * I_ + kt * 32 + lq * 8);
        }
        int offh[4], offx[2], offw[4];
#pragma unroll
        for (int kt = 0; kt < 4; kt++) offh[kt] = ln15 * 128 + (((kt * 4 + lq) ^ ln15) & 15) * 8;
#pragma unroll
        for (int kt = 0; kt < 2; kt++) offx[kt] = ln15 * 64 + (((kt * 4 + lq) ^ (ln15 & 7)) & 7) * 8;
#pragma unroll
        for (int reg = 0; reg < 4; reg++) {
            int row = lq * 4 + reg;
            offw[reg] = row * 128 + (((col >> 3) ^ row) & 15) * 8 + (col & 7);
        }
        float hF[2][4] = {};

#pragma unroll 1
        for (int t = 0; t < T_; t += 2) {
#pragma unroll
            for (int half_ = 0; half_ < 2; half_++) {
                f4 aR[2], aZ[2], aXn[2], aHn[2];
                // ---- group 0: frags + MFMA ----
                {
                    h8 ah[4], axf[2];
#pragma unroll
                    for (int kt = 0; kt < 4; kt++) ah[kt] = *(const h8*)&s_h[half_][0][offh[kt]];
#pragma unroll
                    for (int kt = 0; kt < 2; kt++) axf[kt] = *(const h8*)&s_x[half_][0][offx[kt]];
                    aR[0]  = (f4){seedR, seedR, seedR, seedR};
                    aZ[0]  = (f4){seedZ, seedZ, seedZ, seedZ};
                    aXn[0] = (f4){bihN, bihN, bihN, bihN};
                    aHn[0] = (f4){bhhN, bhhN, bhhN, bhhN};
#pragma unroll
                    for (int kt = 0; kt < 4; kt++) {
                        aR[0]  = __builtin_amdgcn_mfma_f32_16x16x32_f16(ah[kt], bh[0][kt], aR[0], 0, 0, 0);
                        aZ[0]  = __builtin_amdgcn_mfma_f32_16x16x32_f16(ah[kt], bh[1][kt], aZ[0], 0, 0, 0);
                        aHn[0] = __builtin_amdgcn_mfma_f32_16x16x32_f16(ah[kt], bh[2][kt], aHn[0], 0, 0, 0);
                    }
#pragma unroll
                    for (int kt = 0; kt < 2; kt++) {
                        aR[0]  = __builtin_amdgcn_mfma_f32_16x16x32_f16(axf[kt], bx[0][kt], aR[0], 0, 0, 0);
                        aZ[0]  = __builtin_amdgcn_mfma_f32_16x16x32_f16(axf[kt], bx[1][kt], aZ[0], 0, 0, 0);
                        aXn[0] = __builtin_amdgcn_mfma_f32_16x16x32_f16(axf[kt], bx[2][kt], aXn[0], 0, 0, 0);
                    }
                }
                // ---- group 1: frags + MFMA (issues while group 0's chain drains) ----
                {
                    h8 ah[4], axf[2];
#pragma unroll
                    for (int kt = 0; kt < 4; kt++) ah[kt] = *(const h8*)&s_h[half_][1][offh[kt]];
#pragma unroll
                    for (int kt = 0; kt < 2; kt++) axf[kt] = *(const h8*)&s_x[half_][1][offx[kt]];
                    aR[1]  = (f4){seedR, seedR, seedR, seedR};
                    aZ[1]  = (f4){seedZ, seedZ, seedZ, seedZ};
                    aXn[1] = (f4){bihN, bihN, bihN, bihN};
                    aHn[1] = (f4){bhhN, bhhN, bhhN, bhhN};
#pragma unroll
                    for (int kt = 0; kt < 4; kt++) {
                        aR[1]  = __builtin_amdgcn_mfma_f32_16x16x32_f16(ah[kt], bh[0][kt], aR[1], 0, 0, 0);
                        aZ[1]  = __builtin_amdgcn_mfma_f32_16x16x32_f16(ah[kt], bh[1][kt], aZ[1], 0, 0, 0);
                        aHn[1] = __builtin_amdgcn_mfma_f32_16x16x32_f16(ah[kt], bh[2][kt], aHn[1], 0, 0, 0);
                    }
#pragma unroll
                    for (int kt = 0; kt < 2; kt++) {
                        aR[1]  = __builtin_amdgcn_mfma_f32_16x16x32_f16(axf[kt], bx[0][kt], aR[1], 0, 0, 0);
                        aZ[1]  = __builtin_amdgcn_mfma_f32_16x16x32_f16(axf[kt], bx[1][kt], aZ[1], 0, 0, 0);
                        aXn[1] = __builtin_amdgcn_mfma_f32_16x16x32_f16(axf[kt], bx[2][kt], aXn[1], 0, 0, 0);
                    }
                }
                // ---- gates: group 0 (overlaps group 1's MFMA drain), then group 1 ----
#pragma unroll
                for (int g2 = 0; g2 < 2; g2++) {
#pragma unroll
                    for (int reg = 0; reg < 4; reg++) {
                        float r = sigm(aR[g2][reg]);
                        float z = sigm(aZ[g2][reg]);
                        float n = tanh_f(aXn[g2][reg] + r * aHn[g2][reg]);
                        float h = n + z * (hF[g2][reg] - n);
                        hF[g2][reg] = h;
                        s_h[half_ ^ 1][g2][offw[reg]] = (_Float16)h;
                    }
                }
                bar_lds();
            }
        }
    } else {       // ================= PRODUCER =================
        const int pt = tid - 512;            // 0..255
        // out0 stores: 2 granules/thread (32 rows x 16 granules of 8 halfs)
        int roff[2];
        _Float16* obase[2];
#pragma unroll
        for (int k = 0; k < 2; k++) {
            int idx = pt + k * 256;
            int r = idx >> 4, c8 = (idx & 15) * 8;
            int grp = r >> 4, r16 = r & 15;
            roff[k] = grp * (16 * 128) + r16 * 128 + (((c8 >> 3) ^ r16) & 15) * 8;
            obase[k] = out0 + ((size_t)(b0 + r) * T_) * HC + dir * H_ + c8;
        }
        // x staging: 1 granule/thread (32 rows x 8 granules)
        const int xr = pt >> 3, xg = pt & 7;
        const int xgrp = xr >> 4, xr16 = xr & 15;
        const int xoff = xgrp * (16 * 64) + xr16 * 64 + ((xg ^ (xr16 & 7)) & 7) * 8;
        const _Float16* xbase = x16 + ((size_t)(b0 + xr) * T_) * I_ + xg * 8;
        _Float16* s_hflat0 = &s_h[0][0][0];
        _Float16* s_hflat1 = &s_h[1][0][0];
        _Float16* s_xflat0 = &s_x[0][0][0];
        _Float16* s_xflat1 = &s_x[1][0][0];

        h8 pfA = {}, pfB = {};
        {   // prologue: pfA = x(step 1)
            int tn = dir ? (T_ - 2) : 1;
            pfA = *(const h8*)(xbase + (size_t)tn * I_);
        }

#pragma unroll 1
        for (int t = 0; t < T_; t += 2) {
            {   // even step s=t
                *(h8*)&s_xflat1[xoff] = pfA;
                if (t + 2 < T_) {
                    int tn = dir ? (T_ - 3 - t) : (t + 2);
                    pfB = *(const h8*)(xbase + (size_t)tn * I_);
                }
                if (t > 0) {
                    int ttp = dir ? (T_ - t) : (t - 1);
#pragma unroll
                    for (int k = 0; k < 2; k++) {
                        f4 hv = *(const f4*)&s_hflat0[roff[k]];
                        *(f4*)(obase[k] + (size_t)ttp * HC) = hv;
                    }
                }
                bar_lds();
            }
            {   // odd step s=t+1
                if (t + 2 < T_) *(h8*)&s_xflat0[xoff] = pfB;
                if (t + 3 < T_) {
                    int tn = dir ? (T_ - 4 - t) : (t + 3);
                    pfA = *(const h8*)(xbase + (size_t)tn * I_);
                }
                {
                    int s = t + 1;
                    int ttp = dir ? (T_ - s) : (s - 1);
#pragma unroll
                    for (int k = 0; k < 2; k++) {
                        f4 hv = *(const f4*)&s_hflat1[roff[k]];
                        *(f4*)(obase[k] + (size_t)ttp * HC) = hv;
                    }
                }
                bar_lds();
            }
        }
        {   // epilogue: h(T) in buf0 @ time tt(T-1)
            int ttp = dir ? 0 : (T_ - 1);
#pragma unroll
            for (int k = 0; k < 2; k++) {
                f4 hv = *(const f4*)&s_hflat0[roff[k]];
                *(f4*)(obase[k] + (size_t)ttp * HC) = hv;
            }
        }
    }
}

// ---------------- MFMA GEMM v4 (unchanged): per-block M=64, full N=384 ----------------
__launch_bounds__(256, 1)
__global__ void gemm_xw1(const _Float16* __restrict__ A,   // [M][256]
                         const _Float16* __restrict__ Bw,  // [384][256] fp16
                         const float* __restrict__ bias,
                         _Float16* __restrict__ C) {       // [M][384] permuted rows
    __shared__ __align__(16) _Float16 sA[2][64 * 64];
    __shared__ __align__(16) _Float16 sB[2][384 * 64];
    const int tid  = threadIdx.x;
    const int lane = tid & 63;
    const int w    = tid >> 6;
    const int wm   = w & 1, wn = w >> 1;
    const int ln15 = lane & 15, lq = lane >> 4;
    const size_t m0 = (size_t)blockIdx.x * 64;

    f4 acc[2][12] = {};

    int aRow[2], aG[2], aOff[2];
#pragma unroll
    for (int k = 0; k < 2; k++) {
        int idx = k * 256 + tid;
        aRow[k] = idx >> 3; aG[k] = idx & 7;
        aOff[k] = aRow[k] * 64 + ((aG[k] ^ (aRow[k] & 7)) & 7) * 8;
    }
    int bRow[12], bG[12], bOff[12];
#pragma unroll
    for (int k = 0; k < 12; k++) {
        int idx = k * 256 + tid;
        bRow[k] = idx >> 3; bG[k] = idx & 7;
        bOff[k] = bRow[k] * 64 + ((bG[k] ^ (bRow[k] & 7)) & 7) * 8;
    }
    int offA[2][2], offB[12][2];
#pragma unroll
    for (int mt = 0; mt < 2; mt++)
#pragma unroll
        for (int kt = 0; kt < 2; kt++) {
            int row = wm * 32 + mt * 16 + ln15;
            offA[mt][kt] = row * 64 + (((kt * 4 + lq) ^ (row & 7)) & 7) * 8;
        }
#pragma unroll
    for (int nt = 0; nt < 12; nt++)
#pragma unroll
        for (int kt = 0; kt < 2; kt++) {
            int row = wn * 192 + nt * 16 + ln15;
            offB[nt][kt] = row * 64 + (((kt * 4 + lq) ^ (row & 7)) & 7) * 8;
        }

    {
        h8 av[2], bv[12];
#pragma unroll
        for (int k = 0; k < 2; k++) av[k] = *(const h8*)(A + (m0 + aRow[k]) * 256 + aG[k] * 8);
#pragma unroll
        for (int k = 0; k < 12; k++) bv[k] = *(const h8*)(Bw + (size_t)bRow[k] * 256 + bG[k] * 8);
#pragma unroll
        for (int k = 0; k < 2; k++) *(h8*)&sA[0][aOff[k]] = av[k];
#pragma unroll
        for (int k = 0; k < 12; k++) *(h8*)&sB[0][bOff[k]] = bv[k];
        bar_lds();
    }

#pragma unroll
    for (int c = 0; c < 4; c++) {
        const int cur = c & 1;
        h8 av[2], bv[12];
        if (c < 3) {
#pragma unroll
            for (int k = 0; k < 2; k++)
                av[k] = *(const h8*)(A + (m0 + aRow[k]) * 256 + (c + 1) * 64 + aG[k] * 8);
#pragma unroll
            for (int k = 0; k < 12; k++)
                bv[k] = *(const h8*)(Bw + (size_t)bRow[k] * 256 + (c + 1) * 64 + bG[k] * 8);
        }
#pragma unroll
        for (int kt = 0; kt < 2; kt++) {
            h8 af0 = *(const h8*)&sA[cur][offA[0][kt]];
            h8 af1 = *(const h8*)&sA[cur][offA[1][kt]];
#pragma unroll
            for (int nt = 0; nt < 12; nt++) {
                h8 bf = *(const h8*)&sB[cur][offB[nt][kt]];
                acc[0][nt] = __builtin_amdgcn_mfma_f32_16x16x32_f16(af0, bf, acc[0][nt], 0, 0, 0);
                acc[1][nt] = __builtin_amdgcn_mfma_f32_16x16x32_f16(af1, bf, acc[1][nt], 0, 0, 0);
            }
        }
        if (c < 3) {
#pragma unroll
            for (int k = 0; k < 2; k++) *(h8*)&sA[cur ^ 1][aOff[k]] = av[k];
#pragma unroll
            for (int k = 0; k < 12; k++) *(h8*)&sB[cur ^ 1][bOff[k]] = bv[k];
            bar_lds();
        }
    }
#pragma unroll
    for (int nt = 0; nt < 12; nt++) {
        int col = wn * 192 + nt * 16 + ln15;
        float bb = bias[col];
        int pcol = (col < 256) ? ((col & 127) * 2 + (col >> 7)) : col;
#pragma unroll
        for (int mt = 0; mt < 2; mt++) {
            size_t row = m0 + wm * 32 + mt * 16 + lq * 4;
#pragma unroll
            for (int reg = 0; reg < 4; reg++)
                C[(row + reg) * G_ + pcol] = (_Float16)(acc[mt][nt][reg] + bb);
        }
    }
}

// ---------------- Layer-1 fwd scan: TWO independent 16-row groups + ring ----------------
#define RZP 268
#define NP  140
#define NB  (16 * RZP)
#define SLOT (NB + 16 * NP)            // per group, 6528 halfs
__launch_bounds__(768, 1)
__global__ void scan_l1(const _Float16* __restrict__ xw1,
                        const float* __restrict__ Whh,
                        const float* __restrict__ bhh,
                        float* __restrict__ h1f) {
    __shared__ __align__(16) _Float16 s_h[2][2][16 * 128];     // [buf][grp], 16 KB
    __shared__ __align__(16) _Float16 s_ring[2][2][SLOT];      // [slot][grp], 52 KB

    const int tid  = threadIdx.x;
    const int lane = tid & 63;
    const int w    = tid >> 6;
    const int b0   = blockIdx.x * 32;

    {
        _Float16* ph = &s_h[0][0][0];
        for (int i = tid; i < 2 * 16 * 128; i += 768) ph[i] = (_Float16)0.f;
    }

    if (w < 8) {   // ================= COMPUTE =================
        const int ln15 = lane & 15;
        const int lq   = lane >> 4;
        const int col  = 16 * w + ln15;
        h8 bh[3][4];
        float bhhF[3];
#pragma unroll
        for (int g = 0; g < 3; g++) {
            int n = g * H_ + col;
            bhhF[g] = bhh[n];
#pragma unroll
            for (int kt = 0; kt < 4; kt++) bh[g][kt] = load_w8(Whh + (size_t)n * H_ + kt * 32 + lq * 8);
        }
        int offh[4], offw[4], offrz[4], offn[4];
#pragma unroll
        for (int kt = 0; kt < 4; kt++) offh[kt] = ln15 * 128 + (((kt * 4 + lq) ^ ln15) & 15) * 8;
#pragma unroll
        for (int reg = 0; reg < 4; reg++) {
            int row = lq * 4 + reg;
            offw[reg]  = row * 128 + (((col >> 3) ^ row) & 15) * 8 + (col & 7);
            offrz[reg] = row * RZP + col * 2;
            offn[reg]  = NB + row * NP + col;
        }
        float hF[2][4] = {};
        __syncthreads();

#pragma unroll 1
        for (int t = 0; t < T_; t += 2) {
#pragma unroll
            for (int half_ = 0; half_ < 2; half_++) {
                f4 aH[2][3];
                // group 0 MFMA
                {
                    h8 ah[4];
#pragma unroll
                    for (int kt = 0; kt < 4; kt++) ah[kt] = *(const h8*)&s_h[half_][0][offh[kt]];
#pragma unroll
                    for (int g = 0; g < 3; g++) aH[0][g] = (f4){bhhF[g], bhhF[g], bhhF[g], bhhF[g]};
#pragma unroll
                    for (int kt = 0; kt < 4; kt++) {
                        aH[0][0] = __builtin_amdgcn_mfma_f32_16x16x32_f16(ah[kt], bh[0][kt], aH[0][0], 0, 0, 0);
                        aH[0][1] = __builtin_amdgcn_mfma_f32_16x16x32_f16(ah[kt], bh[1][kt], aH[0][1], 0, 0, 0);
                        aH[0][2] = __builtin_amdgcn_mfma_f32_16x16x32_f16(ah[kt], bh[2][kt], aH[0][2], 0, 0, 0);
                    }
                }
                // group 1 MFMA
                {
                    h8 ah[4];
#pragma unroll
                    for (int kt = 0; kt < 4; kt++) ah[kt] = *(const h8*)&s_h[half_][1][offh[kt]];
#pragma unroll
                    for (int g = 0; g < 3; g++) aH[1][g] = (f4){bhhF[g], bhhF[g], bhhF[g], bhhF[g]};
#pragma unroll
                    for (int kt = 0; kt < 4; kt++) {
                        aH[1][0] = __builtin_amdgcn_mfma_f32_16x16x32_f16(ah[kt], bh[0][kt], aH[1][0], 0, 0, 0);
                        aH[1][1] = __builtin_amdgcn_mfma_f32_16x16x32_f16(ah[kt], bh[1][kt], aH[1][1], 0, 0, 0);
                        aH[1][2] = __builtin_amdgcn_mfma_f32_16x16x32_f16(ah[kt], bh[2][kt], aH[1][2], 0, 0, 0);
                    }
                }
                // gates both groups
#pragma unroll
                for (int g2 = 0; g2 < 2; g2++) {
#pragma unroll
                    for (int reg = 0; reg < 4; reg++) {
                        h2 rz = *(const h2*)&s_ring[half_][g2][offrz[reg]];
                        float xn = (float)s_ring[half_][g2][offn[reg]];
                        float r = sigm((float)rz[0] + aH[g2][0][reg]);
                        float z = sigm((float)rz[1] + aH[g2][1][reg]);
                        float n = tanh_f(xn + r * aH[g2][2][reg]);
                        float h = n + z * (hF[g2][reg] - n);
                        hF[g2][reg] = h;
                        s_h[half_ ^ 1][g2][offw[reg]] = (_Float16)h;
                    }
                }
                bar_lds();
            }
        }
#pragma unroll
        for (int g2 = 0; g2 < 2; g2++)
#pragma unroll
            for (int reg = 0; reg < 4; reg++)
                h1f[(size_t)(b0 + g2 * 16 + lq * 4 + reg) * H_ + col] = hF[g2][reg];
    } else {       // ================= PRODUCER (ring staging, 12 chunks) =================
        const int pt = tid - 512;
        const _Float16* sgb[12];
        int dstoff[12];
#pragma unroll
        for (int k = 0; k < 12; k++) {
            int ch = pt + k * 256;              // 3072 chunks of 4 halfs (32 rows x 96)
            int sRow = ch / 96;
            int grp = sRow >> 4, r16 = sRow & 15;
            int c4 = (ch % 96) * 4;
            sgb[k] = xw1 + (size_t)(b0 + sRow) * T_ * G_ + c4;
            dstoff[k] = grp * SLOT + ((c4 < 256) ? (r16 * RZP + c4) : (NB + r16 * NP + (c4 - 256)));
        }
        _Float16* ring0 = &s_ring[0][0][0];
        _Float16* ring1 = &s_ring[1][0][0];
        float2 pfA[12], pfB[12];
#pragma unroll
        for (int k = 0; k < 12; k++) {
            float2 v = *(const float2*)(sgb[k]);
            *(float2*)&ring0[dstoff[k]] = v;
            pfA[k] = *(const float2*)(sgb[k] + G_);
        }
        __syncthreads();

#pragma unroll 1
        for (int t = 0; t < T_; t += 2) {
            if (t + 2 < T_) {
#pragma unroll
                for (int k = 0; k < 12; k++) pfB[k] = *(const float2*)(sgb[k] + (size_t)(t + 2) * G_);
            }
#pragma unroll
            for (int k = 0; k < 12; k++) *(float2*)&ring1[dstoff[k]] = pfA[k];
            bar_lds();
            if (t + 3 < T_) {
#pragma unroll
                for (int k = 0; k < 12; k++) pfA[k] = *(const float2*)(sgb[k] + (size_t)(t + 3) * G_);
            }
            if (t + 2 < T_) {
#pragma unroll
                for (int k = 0; k < 12; k++) *(float2*)&ring0[dstoff[k]] = pfB[k];
            }
            bar_lds();
        }
    }
}

// ---------------- Tail: layer-1 bwd single step + relu + FC ----------------
__launch_bounds__(384)
__global__ void final_k(const _Float16* __restrict__ out0,
                        const float* __restrict__ h1f,
                        const __half2* __restrict__ w1b,
                        const float* __restrict__ bih1b, const float* __restrict__ bhh1b,
                        const float* __restrict__ fcw, const float* __restrict__ fcb,
                        float* __restrict__ out) {
    __shared__ __align__(16) float s_x1[HC];
    __shared__ __align__(16) float s_xw[G_];
    __shared__ __align__(16) float s_hc[HC];
    __shared__ float s_red[8];
    const int tid = threadIdx.x;
    const int b = blockIdx.x;
    if (tid < HC)
        s_x1[tid] = (float)out0[((size_t)b * T_ + (T_ - 1)) * HC + tid];
    __syncthreads();
    {
        float acc0 = 0.f, acc1 = 0.f;
        const float2* xv = (const float2*)s_x1;
#pragma unroll 8
        for (int k2 = 0; k2 < 128; k2 += 2) {
            float2 w0 = __half22float2(w1b[k2 * G_ + tid]);
            float2 w1 = __half22float2(w1b[(k2 + 1) * G_ + tid]);
            float2 a0 = xv[k2], a1 = xv[k2 + 1];
            acc0 += a0.x * w0.x + a0.y * w0.y;
            acc1 += a1.x * w1.x + a1.y * w1.y;
        }
        s_xw[tid] = bih1b[tid] + acc0 + acc1;
    }
    __syncthreads();
    if (tid < H_) {
        int j = tid;
        float rg = sigm(s_xw[j] + bhh1b[j]);
        float zg = sigm(s_xw[H_ + j] + bhh1b[H_ + j]);
        float ng = tanh_f(s_xw[2 * H_ + j] + rg * bhh1b[2 * H_ + j]);
        float hb = (1.f - zg) * ng;
        s_hc[H_ + j] = fmaxf(hb, 0.f);
        s_hc[j] = fmaxf(h1f[(size_t)b * H_ + j], 0.f);
    }
    __syncthreads();
    if (tid < HC) {
        float hv = s_hc[tid];
        float p0 = hv * fcw[tid];
        float p1 = hv * fcw[HC + tid];
#pragma unroll
        for (int off = 32; off; off >>= 1) {
            p0 += __shfl_down(p0, off);
            p1 += __shfl_down(p1, off);
        }
        if ((tid & 63) == 0) { s_red[(tid >> 6) * 2] = p0; s_red[(tid >> 6) * 2 + 1] = p1; }
    }
    __syncthreads();
    if (tid == 0) {
        out[b * 2 + 0] = fcb[0] + s_red[0] + s_red[2] + s_red[4] + s_red[6];
        out[b * 2 + 1] = fcb[1] + s_red[1] + s_red[3] + s_red[5] + s_red[7];
    }
}

extern "C" void kernel_launch(void* const* d_in, const int* in_sizes, int n_in,
                              void* d_out, int out_size, void* d_ws, size_t ws_size,
                              hipStream_t stream) {
    (void)in_sizes; (void)n_in; (void)out_size; (void)ws_size;
    const float* x     = (const float*)d_in[0];
    const float* Wih0f = (const float*)d_in[1];
    const float* Whh0f = (const float*)d_in[2];
    const float* bih0f = (const float*)d_in[3];
    const float* bhh0f = (const float*)d_in[4];
    const float* Wih0b = (const float*)d_in[5];
    const float* Whh0b = (const float*)d_in[6];
    const float* bih0b = (const float*)d_in[7];
    const float* bhh0b = (const float*)d_in[8];
    const float* Wih1f = (const float*)d_in[9];
    const float* Whh1f = (const float*)d_in[10];
    const float* bih1f = (const float*)d_in[11];
    const float* bhh1f = (const float*)d_in[12];
    const float* Wih1b = (const float*)d_in[13];
    const float* bih1b = (const float*)d_in[15];
    const float* bhh1b = (const float*)d_in[16];
    const float* fcw   = (const float*)d_in[17];
    const float* fcb   = (const float*)d_in[18];

    char* ws = (char*)d_ws;
    _Float16* out0 = (_Float16*)(ws + O_OUT0);
    _Float16* xw1  = (_Float16*)(ws + O_XW1);
    _Float16* x16  = (_Float16*)(ws + O_X16);
    __half2*  wp   = (__half2*)(ws + O_WP);
    float*    h1f  = (float*)(ws + O_H1F);
    _Float16* wf16 = (_Float16*)(ws + O_WF16);
    float*    out  = (float*)d_out;

    prep<<<4336, 256, 0, stream>>>(x, x16, Wih1f, wf16, Wih1b, wp);

    scan_l0<<<dim3(8, 2), 768, 0, stream>>>(x16, Wih0f, Whh0f, bih0f, bhh0f,
                                            Wih0b, Whh0b, bih0b, bhh0b, out0);

    gemm_xw1<<<2048, 256, 0, stream>>>(out0, wf16, bih1f, xw1);

    scan_l1<<<8, 768, 0, stream>>>(xw1, Whh1f, bhh1f, h1f);

    final_k<<<256, 384, 0, stream>>>(out0, h1f, wp, bih1b, bhh1b, fcw, fcb, out);
}

// Round 12
// 822.065 us; speedup vs baseline: 1.7865x; 1.7865x over previous
//
#include <hip/hip_runtime.h>
#include <hip/hip_fp16.h>

#define B_  256
#define T_  512
#define I_  64
#define H_  128
#define G_  384
#define HC  256

// Workspace layout (stream-ordered aliasing: x16 occupies the head of the xw1
// region — gemm overwrites it only after scan_l0 has fully consumed x16).
#define O_OUT0 0ull                    // fp16 [B][T][2H] = 67,108,864
#define O_XW1  67108864ull             // fp16 [B][T][3H] = 100,663,296 (xw1; x16 aliases head)
#define O_X16  O_XW1                   // fp16 [B][T][64] = 16,777,216 (until gemm runs)
#define O_WP   167772160ull            // packed half2 Wih1b, 196,608
#define O_H1F  (O_WP + 196608ull)      // f32 [B][H] = 131,072
#define O_WF16 (O_H1F + 131072ull)     // fp16 Wih1f [384][256] = 196,608

typedef _Float16 h8 __attribute__((ext_vector_type(8)));
typedef _Float16 h2 __attribute__((ext_vector_type(2)));
typedef float    f4 __attribute__((ext_vector_type(4)));

__device__ __forceinline__ float sigm(float x)   { return __builtin_amdgcn_rcpf(1.f + __expf(-x)); }
__device__ __forceinline__ float tanh_f(float x) { return 1.f - 2.f * __builtin_amdgcn_rcpf(1.f + __expf(2.f * x)); }

// LDS-only barrier: waits lgkmcnt(0) but NOT vmcnt.
__device__ __forceinline__ void bar_lds() {
    asm volatile("s_waitcnt lgkmcnt(0)\n\ts_barrier" ::: "memory");
}

__device__ __forceinline__ h8 load_w8(const float* src) {
    f4 a = *(const f4*)src;
    f4 b = *(const f4*)(src + 4);
    h8 v;
    v[0]=(_Float16)a[0]; v[1]=(_Float16)a[1]; v[2]=(_Float16)a[2]; v[3]=(_Float16)a[3];
    v[4]=(_Float16)b[0]; v[5]=(_Float16)b[1]; v[6]=(_Float16)b[2]; v[7]=(_Float16)b[3];
    return v;
}

// Fused prep: x->fp16 (4096 blocks), Wih1f->fp16 (48), Wih1b pack-T (192).
__global__ void prep(const float* __restrict__ x, _Float16* __restrict__ x16,
                     const float* __restrict__ Wf, _Float16* __restrict__ wf16,
                     const float* __restrict__ W1b, __half2* __restrict__ wp) {
    const int bid = blockIdx.x;
    const int tid = threadIdx.x;
    if (bid < 4096) {
        int i = bid * 256 + tid;
        const float* s = x + (size_t)i * 8;
        f4 a = *(const f4*)s, b = *(const f4*)(s + 4);
        h8 v;
        v[0]=(_Float16)a[0]; v[1]=(_Float16)a[1]; v[2]=(_Float16)a[2]; v[3]=(_Float16)a[3];
        v[4]=(_Float16)b[0]; v[5]=(_Float16)b[1]; v[6]=(_Float16)b[2]; v[7]=(_Float16)b[3];
        *(h8*)(x16 + (size_t)i * 8) = v;
    } else if (bid < 4144) {
        int i = (bid - 4096) * 256 + tid;
        const float* s = Wf + (size_t)i * 8;
        f4 a = *(const f4*)s, b = *(const f4*)(s + 4);
        h8 v;
        v[0]=(_Float16)a[0]; v[1]=(_Float16)a[1]; v[2]=(_Float16)a[2]; v[3]=(_Float16)a[3];
        v[4]=(_Float16)b[0]; v[5]=(_Float16)b[1]; v[6]=(_Float16)b[2]; v[7]=(_Float16)b[3];
        *(h8*)(wf16 + (size_t)i * 8) = v;
    } else {
        int i = (bid - 4144) * 256 + tid;
        int c = i % G_;
        int k2 = i / G_;
        wp[i] = __halves2half2(__float2half(W1b[c * 256 + 2 * k2]),
                               __float2half(W1b[c * 256 + 2 * k2 + 1]));
    }
}

// ---------------- Layer-0 scan: wave-specialized, distance-1 x prefetch (R10) ----------------
__launch_bounds__(768, 1)
__global__ void scan_l0(const _Float16* __restrict__ x16,
                        const float* __restrict__ Wih_f, const float* __restrict__ Whh_f,
                        const float* __restrict__ bih_f, const float* __restrict__ bhh_f,
                        const float* __restrict__ Wih_b, const float* __restrict__ Whh_b,
                        const float* __restrict__ bih_b, const float* __restrict__ bhh_b,
                        _Float16* __restrict__ out0) {
    __shared__ __align__(16) _Float16 s_h[2][16 * 128];
    __shared__ __align__(16) _Float16 s_x[2][16 * 64];

    const int tid  = threadIdx.x;
    const int lane = tid & 63;
    const int w    = tid >> 6;
    const int dir  = blockIdx.y;
    const int b0   = blockIdx.x * 16;

    const float* Wih = dir ? Wih_b : Wih_f;
    const float* Whh = dir ? Whh_b : Whh_f;
    const float* bih = dir ? bih_b : bih_f;
    const float* bhh = dir ? bhh_b : bhh_f;

    {
        for (int i = tid; i < 16 * 128; i += 768) s_h[0][i] = (_Float16)0.f;
        if (w >= 8) {
            int pt = tid - 512;
            if (pt < 128) {
                int xr = pt >> 3, xg = pt & 7;
                int t0 = dir ? (T_ - 1) : 0;
                h8 v = *(const h8*)(x16 + ((size_t)(b0 + xr) * T_ + t0) * I_ + xg * 8);
                *(h8*)&s_x[0][xr * 64 + ((xg ^ (xr & 7)) & 7) * 8] = v;
            }
        }
    }
    __syncthreads();

    if (w < 8) {   // ================= COMPUTE =================
        const int ln15 = lane & 15;
        const int lq   = lane >> 4;
        const int col  = 16 * w + ln15;
        h8 bh[3][4], bx[3][2];
        float seedR = bih[col] + bhh[col];
        float seedZ = bih[H_ + col] + bhh[H_ + col];
        float bihN  = bih[2 * H_ + col];
        float bhhN  = bhh[2 * H_ + col];
#pragma unroll
        for (int g = 0; g < 3; g++) {
            int n = g * H_ + col;
#pragma unroll
            for (int kt = 0; kt < 4; kt++) bh[g][kt] = load_w8(Whh + (size_t)n * H_ + kt * 32 + lq * 8);
#pragma unroll
            for (int kt = 0; kt < 2; kt++) bx[g][kt] = load_w8(Wih + (size_t)n * I_ + kt * 32 + lq * 8);
        }
        int offh[4], offx[2], offw[4];
#pragma unroll
        for (int kt = 0; kt < 4; kt++) offh[kt] = ln15 * 128 + (((kt * 4 + lq) ^ ln15) & 15) * 8;
#pragma unroll
        for (int kt = 0; kt < 2; kt++) offx[kt] = ln15 * 64 + (((kt * 4 + lq) ^ (ln15 & 7)) & 7) * 8;
#pragma unroll
        for (int reg = 0; reg < 4; reg++) {
            int row = lq * 4 + reg;
            offw[reg] = row * 128 + (((col >> 3) ^ row) & 15) * 8 + (col & 7);
        }
        float hF[4] = {0.f, 0.f, 0.f, 0.f};

#pragma unroll 1
        for (int t = 0; t < T_; t += 2) {
#pragma unroll
            for (int half_ = 0; half_ < 2; half_++) {
                h8 ah[4], axf[2];
#pragma unroll
                for (int kt = 0; kt < 4; kt++) ah[kt] = *(const h8*)&s_h[half_][offh[kt]];
#pragma unroll
                for (int kt = 0; kt < 2; kt++) axf[kt] = *(const h8*)&s_x[half_][offx[kt]];
                f4 aR  = (f4){seedR, seedR, seedR, seedR};
                f4 aZ  = (f4){seedZ, seedZ, seedZ, seedZ};
                f4 aXn = (f4){bihN, bihN, bihN, bihN};
                f4 aHn = (f4){bhhN, bhhN, bhhN, bhhN};
#pragma unroll
                for (int kt = 0; kt < 4; kt++) {
                    aR  = __builtin_amdgcn_mfma_f32_16x16x32_f16(ah[kt], bh[0][kt], aR, 0, 0, 0);
                    aZ  = __builtin_amdgcn_mfma_f32_16x16x32_f16(ah[kt], bh[1][kt], aZ, 0, 0, 0);
                    aHn = __builtin_amdgcn_mfma_f32_16x16x32_f16(ah[kt], bh[2][kt], aHn, 0, 0, 0);
                }
#pragma unroll
                for (int kt = 0; kt < 2; kt++) {
                    aR  = __builtin_amdgcn_mfma_f32_16x16x32_f16(axf[kt], bx[0][kt], aR, 0, 0, 0);
                    aZ  = __builtin_amdgcn_mfma_f32_16x16x32_f16(axf[kt], bx[1][kt], aZ, 0, 0, 0);
                    aXn = __builtin_amdgcn_mfma_f32_16x16x32_f16(axf[kt], bx[2][kt], aXn, 0, 0, 0);
                }
#pragma unroll
                for (int reg = 0; reg < 4; reg++) {
                    float r = sigm(aR[reg]);
                    float z = sigm(aZ[reg]);
                    float n = tanh_f(aXn[reg] + r * aHn[reg]);
                    float h = n + z * (hF[reg] - n);
                    hF[reg] = h;
                    s_h[half_ ^ 1][offw[reg]] = (_Float16)h;
                }
                bar_lds();
            }
        }
    } else {       // ================= PRODUCER =================
        const int pt = tid - 512;
        const int r  = pt >> 4;
        const int c8 = (pt & 15) * 8;
        const int roff = r * 128 + (((c8 >> 3) ^ r) & 15) * 8;
        _Float16* obase = out0 + ((size_t)(b0 + r) * T_) * HC + dir * H_ + c8;
        const int xr = pt >> 3, xg = pt & 7;
        const int xoff = xr * 64 + ((xg ^ (xr & 7)) & 7) * 8;
        const _Float16* xbase = x16 + ((size_t)(b0 + xr) * T_) * I_ + xg * 8;

        h8 pfA = {}, pfB = {};
        if (pt < 128) {
            int tn = dir ? (T_ - 2) : 1;
            pfA = *(const h8*)(xbase + (size_t)tn * I_);
        }

#pragma unroll 1
        for (int t = 0; t < T_; t += 2) {
            {
                if (pt < 128) {
                    *(h8*)&s_x[1][xoff] = pfA;
                    if (t + 2 < T_) {
                        int tn = dir ? (T_ - 3 - t) : (t + 2);
                        pfB = *(const h8*)(xbase + (size_t)tn * I_);
                    }
                }
                if (t > 0) {
                    int ttp = dir ? (T_ - t) : (t - 1);
                    f4 hv = *(const f4*)&s_h[0][roff];
                    *(f4*)(obase + (size_t)ttp * HC) = hv;
                }
                bar_lds();
            }
            {
                if (pt < 128) {
                    if (t + 2 < T_) *(h8*)&s_x[0][xoff] = pfB;
                    if (t + 3 < T_) {
                        int tn = dir ? (T_ - 4 - t) : (t + 3);
                        pfA = *(const h8*)(xbase + (size_t)tn * I_);
                    }
                }
                {
                    int s = t + 1;
                    int ttp = dir ? (T_ - s) : (s - 1);
                    f4 hv = *(const f4*)&s_h[1][roff];
                    *(f4*)(obase + (size_t)ttp * HC) = hv;
                }
                bar_lds();
            }
        }
        {
            int ttp = dir ? 0 : (T_ - 1);
            f4 hv = *(const f4*)&s_h[0][roff];
            *(f4*)(obase + (size_t)ttp * HC) = hv;
        }
    }
}

// ---------------- MFMA GEMM v4 (R10): per-block M=64, full N=384 ----------------
__launch_bounds__(256, 1)
__global__ void gemm_xw1(const _Float16* __restrict__ A,   // [M][256]
                         const _Float16* __restrict__ Bw,  // [384][256] fp16
                         const float* __restrict__ bias,
                         _Float16* __restrict__ C) {       // [M][384] permuted rows
    __shared__ __align__(16) _Float16 sA[2][64 * 64];
    __shared__ __align__(16) _Float16 sB[2][384 * 64];
    const int tid  = threadIdx.x;
    const int lane = tid & 63;
    const int w    = tid >> 6;
    const int wm   = w & 1, wn = w >> 1;
    const int ln15 = lane & 15, lq = lane >> 4;
    const size_t m0 = (size_t)blockIdx.x * 64;

    f4 acc[2][12] = {};

    int aRow[2], aG[2], aOff[2];
#pragma unroll
    for (int k = 0; k < 2; k++) {
        int idx = k * 256 + tid;
        aRow[k] = idx >> 3; aG[k] = idx & 7;
        aOff[k] = aRow[k] * 64 + ((aG[k] ^ (aRow[k] & 7)) & 7) * 8;
    }
    int bRow[12], bG[12], bOff[12];
#pragma unroll
    for (int k = 0; k < 12; k++) {
        int idx = k * 256 + tid;
        bRow[k] = idx >> 3; bG[k] = idx & 7;
        bOff[k] = bRow[k] * 64 + ((bG[k] ^ (bRow[k] & 7)) & 7) * 8;
    }
    int offA[2][2], offB[12][2];
#pragma unroll
    for (int mt = 0; mt < 2; mt++)
#pragma unroll
        for (int kt = 0; kt < 2; kt++) {
            int row = wm * 32 + mt * 16 + ln15;
            offA[mt][kt] = row * 64 + (((kt * 4 + lq) ^ (row & 7)) & 7) * 8;
        }
#pragma unroll
    for (int nt = 0; nt < 12; nt++)
#pragma unroll
        for (int kt = 0; kt < 2; kt++) {
            int row = wn * 192 + nt * 16 + ln15;
            offB[nt][kt] = row * 64 + (((kt * 4 + lq) ^ (row & 7)) & 7) * 8;
        }

    {
        h8 av[2], bv[12];
#pragma unroll
        for (int k = 0; k < 2; k++) av[k] = *(const h8*)(A + (m0 + aRow[k]) * 256 + aG[k] * 8);
#pragma unroll
        for (int k = 0; k < 12; k++) bv[k] = *(const h8*)(Bw + (size_t)bRow[k] * 256 + bG[k] * 8);
#pragma unroll
        for (int k = 0; k < 2; k++) *(h8*)&sA[0][aOff[k]] = av[k];
#pragma unroll
        for (int k = 0; k < 12; k++) *(h8*)&sB[0][bOff[k]] = bv[k];
        bar_lds();
    }

#pragma unroll
    for (int c = 0; c < 4; c++) {
        const int cur = c & 1;
        h8 av[2], bv[12];
        if (c < 3) {
#pragma unroll
            for (int k = 0; k < 2; k++)
                av[k] = *(const h8*)(A + (m0 + aRow[k]) * 256 + (c + 1) * 64 + aG[k] * 8);
#pragma unroll
            for (int k = 0; k < 12; k++)
                bv[k] = *(const h8*)(Bw + (size_t)bRow[k] * 256 + (c + 1) * 64 + bG[k] * 8);
        }
#pragma unroll
        for (int kt = 0; kt < 2; kt++) {
            h8 af0 = *(const h8*)&sA[cur][offA[0][kt]];
            h8 af1 = *(const h8*)&sA[cur][offA[1][kt]];
#pragma unroll
            for (int nt = 0; nt < 12; nt++) {
                h8 bf = *(const h8*)&sB[cur][offB[nt][kt]];
                acc[0][nt] = __builtin_amdgcn_mfma_f32_16x16x32_f16(af0, bf, acc[0][nt], 0, 0, 0);
                acc[1][nt] = __builtin_amdgcn_mfma_f32_16x16x32_f16(af1, bf, acc[1][nt], 0, 0, 0);
            }
        }
        if (c < 3) {
#pragma unroll
            for (int k = 0; k < 2; k++) *(h8*)&sA[cur ^ 1][aOff[k]] = av[k];
#pragma unroll
            for (int k = 0; k < 12; k++) *(h8*)&sB[cur ^ 1][bOff[k]] = bv[k];
            bar_lds();
        }
    }
#pragma unroll
    for (int nt = 0; nt < 12; nt++) {
        int col = wn * 192 + nt * 16 + ln15;
        float bb = bias[col];
        int pcol = (col < 256) ? ((col & 127) * 2 + (col >> 7)) : col;
#pragma unroll
        for (int mt = 0; mt < 2; mt++) {
            size_t row = m0 + wm * 32 + mt * 16 + lq * 4;
#pragma unroll
            for (int reg = 0; reg < 4; reg++)
                C[(row + reg) * G_ + pcol] = (_Float16)(acc[mt][nt][reg] + bb);
        }
    }
}

// ---------------- Layer-1 fwd scan (R10 + hoisted ring reads) ----------------
#define RZP 268
#define NP  140
#define NB  (16 * RZP)
#define SLOT (NB + 16 * NP)
__launch_bounds__(768, 1)
__global__ void scan_l1(const _Float16* __restrict__ xw1,
                        const float* __restrict__ Whh,
                        const float* __restrict__ bhh,
                        float* __restrict__ h1f) {
    __shared__ __align__(16) _Float16 s_h[2][16 * 128];
    __shared__ __align__(16) _Float16 s_ring[2][SLOT];

    const int tid  = threadIdx.x;
    const int lane = tid & 63;
    const int w    = tid >> 6;
    const int b0   = blockIdx.x * 16;

    {
        for (int i = tid; i < 16 * 128; i += 768) s_h[0][i] = (_Float16)0.f;
    }

    if (w < 8) {   // ================= COMPUTE =================
        const int ln15 = lane & 15;
        const int lq   = lane >> 4;
        const int col  = 16 * w + ln15;
        h8 bh[3][4];
        float bhhF[3];
#pragma unroll
        for (int g = 0; g < 3; g++) {
            int n = g * H_ + col;
            bhhF[g] = bhh[n];
#pragma unroll
            for (int kt = 0; kt < 4; kt++) bh[g][kt] = load_w8(Whh + (size_t)n * H_ + kt * 32 + lq * 8);
        }
        int offh[4], offw[4], offrz[4], offn[4];
#pragma unroll
        for (int kt = 0; kt < 4; kt++) offh[kt] = ln15 * 128 + (((kt * 4 + lq) ^ ln15) & 15) * 8;
#pragma unroll
        for (int reg = 0; reg < 4; reg++) {
            int row = lq * 4 + reg;
            offw[reg]  = row * 128 + (((col >> 3) ^ row) & 15) * 8 + (col & 7);
            offrz[reg] = row * RZP + col * 2;
            offn[reg]  = NB + row * NP + col;
        }
        float hF[4] = {0.f, 0.f, 0.f, 0.f};
        __syncthreads();

#pragma unroll 1
        for (int t = 0; t < T_; t += 2) {
#pragma unroll
            for (int half_ = 0; half_ < 2; half_++) {
                // hoisted: ring gate-operands for THIS step are ready at the
                // barrier — issue their ds_reads first so they drain under MFMA
                h2 rz[4]; _Float16 xnh[4];
#pragma unroll
                for (int reg = 0; reg < 4; reg++) {
                    rz[reg]  = *(const h2*)&s_ring[half_][offrz[reg]];
                    xnh[reg] = s_ring[half_][offn[reg]];
                }
                h8 ah[4];
#pragma unroll
                for (int kt = 0; kt < 4; kt++) ah[kt] = *(const h8*)&s_h[half_][offh[kt]];
                f4 aH[3];
#pragma unroll
                for (int g = 0; g < 3; g++) aH[g] = (f4){bhhF[g], bhhF[g], bhhF[g], bhhF[g]};
#pragma unroll
                for (int kt = 0; kt < 4; kt++) {
                    aH[0] = __builtin_amdgcn_mfma_f32_16x16x32_f16(ah[kt], bh[0][kt], aH[0], 0, 0, 0);
                    aH[1] = __builtin_amdgcn_mfma_f32_16x16x32_f16(ah[kt], bh[1][kt], aH[1], 0, 0, 0);
                    aH[2] = __builtin_amdgcn_mfma_f32_16x16x32_f16(ah[kt], bh[2][kt], aH[2], 0, 0, 0);
                }
#pragma unroll
                for (int reg = 0; reg < 4; reg++) {
                    float r = sigm((float)rz[reg][0] + aH[0][reg]);
                    float z = sigm((float)rz[reg][1] + aH[1][reg]);
                    float n = tanh_f((float)xnh[reg] + r * aH[2][reg]);
                    float h = n + z * (hF[reg] - n);
                    hF[reg] = h;
                    s_h[half_ ^ 1][offw[reg]] = (_Float16)h;
                }
                bar_lds();
            }
        }
#pragma unroll
        for (int reg = 0; reg < 4; reg++)
            h1f[(size_t)(b0 + lq * 4 + reg) * H_ + col] = hF[reg];
    } else {       // ================= PRODUCER (ring staging) =================
        const int pt = tid - 512;
        const _Float16* sgb[6];
        int dstoff[6];
#pragma unroll
        for (int k = 0; k < 6; k++) {
            int ch = pt + k * 256;
            int sRow = ch / 96;
            int c4 = (ch % 96) * 4;
            sgb[k] = xw1 + (size_t)(b0 + sRow) * T_ * G_ + c4;
            dstoff[k] = (c4 < 256) ? (sRow * RZP + c4) : (NB + sRow * NP + (c4 - 256));
        }
        float2 pfA[6], pfB[6];
#pragma unroll
        for (int k = 0; k < 6; k++) {
            float2 v = *(const float2*)(sgb[k]);
            *(float2*)&s_ring[0][dstoff[k]] = v;
            pfA[k] = *(const float2*)(sgb[k] + G_);
        }
        __syncthreads();

#pragma unroll 1
        for (int t = 0; t < T_; t += 2) {
            if (t + 2 < T_) {
#pragma unroll
                for (int k = 0; k < 6; k++) pfB[k] = *(const float2*)(sgb[k] + (size_t)(t + 2) * G_);
            }
#pragma unroll
            for (int k = 0; k < 6; k++) *(float2*)&s_ring[1][dstoff[k]] = pfA[k];
            bar_lds();
            if (t + 3 < T_) {
#pragma unroll
                for (int k = 0; k < 6; k++) pfA[k] = *(const float2*)(sgb[k] + (size_t)(t + 3) * G_);
            }
            if (t + 2 < T_) {
#pragma unroll
                for (int k = 0; k < 6; k++) *(float2*)&s_ring[0][dstoff[k]] = pfB[k];
            }
            bar_lds();
        }
    }
}

// ---------------- Tail: layer-1 bwd single step + relu + FC ----------------
__launch_bounds__(384)
__global__ void final_k(const _Float16* __restrict__ out0,
                        const float* __restrict__ h1f,
                        const __half2* __restrict__ w1b,
                        const float* __restrict__ bih1b, const float* __restrict__ bhh1b,
                        const float* __restrict__ fcw, const float* __restrict__ fcb,
                        float* __restrict__ out) {
    __shared__ __align__(16) float s_x1[HC];
    __shared__ __align__(16) float s_xw[G_];
    __shared__ __align__(16) float s_hc[HC];
    __shared__ float s_red[8];
    const int tid = threadIdx.x;
    const int b = blockIdx.x;
    if (tid < HC)
        s_x1[tid] = (float)out0[((size_t)b * T_ + (T_ - 1)) * HC + tid];
    __syncthreads();
    {
        float acc0 = 0.f, acc1 = 0.f;
        const float2* xv = (const float2*)s_x1;
#pragma unroll 8
        for (int k2 = 0; k2 < 128; k2 += 2) {
            float2 w0 = __half22float2(w1b[k2 * G_ + tid]);
            float2 w1 = __half22float2(w1b[(k2 + 1) * G_ + tid]);
            float2 a0 = xv[k2], a1 = xv[k2 + 1];
            acc0 += a0.x * w0.x + a0.y * w0.y;
            acc1 += a1.x * w1.x + a1.y * w1.y;
        }
        s_xw[tid] = bih1b[tid] + acc0 + acc1;
    }
    __syncthreads();
    if (tid < H_) {
        int j = tid;
        float rg = sigm(s_xw[j] + bhh1b[j]);
        float zg = sigm(s_xw[H_ + j] + bhh1b[H_ + j]);
        float ng = tanh_f(s_xw[2 * H_ + j] + rg * bhh1b[2 * H_ + j]);
        float hb = (1.f - zg) * ng;
        s_hc[H_ + j] = fmaxf(hb, 0.f);
        s_hc[j] = fmaxf(h1f[(size_t)b * H_ + j], 0.f);
    }
    __syncthreads();
    if (tid < HC) {
        float hv = s_hc[tid];
        float p0 = hv * fcw[tid];
        float p1 = hv * fcw[HC + tid];
#pragma unroll
        for (int off = 32; off; off >>= 1) {
            p0 += __shfl_down(p0, off);
            p1 += __shfl_down(p1, off);
        }
        if ((tid & 63) == 0) { s_red[(tid >> 6) * 2] = p0; s_red[(tid >> 6) * 2 + 1] = p1; }
    }
    __syncthreads();
    if (tid == 0) {
        out[b * 2 + 0] = fcb[0] + s_red[0] + s_red[2] + s_red[4] + s_red[6];
        out[b * 2 + 1] = fcb[1] + s_red[1] + s_red[3] + s_red[5] + s_red[7];
    }
}

extern "C" void kernel_launch(void* const* d_in, const int* in_sizes, int n_in,
                              void* d_out, int out_size, void* d_ws, size_t ws_size,
                              hipStream_t stream) {
    (void)in_sizes; (void)n_in; (void)out_size; (void)ws_size;
    const float* x     = (const float*)d_in[0];
    const float* Wih0f = (const float*)d_in[1];
    const float* Whh0f = (const float*)d_in[2];
    const float* bih0f = (const float*)d_in[3];
    const float* bhh0f = (const float*)d_in[4];
    const float* Wih0b = (const float*)d_in[5];
    const float* Whh0b = (const float*)d_in[6];
    const float* bih0b = (const float*)d_in[7];
    const float* bhh0b = (const float*)d_in[8];
    const float* Wih1f = (const float*)d_in[9];
    const float* Whh1f = (const float*)d_in[10];
    const float* bih1f = (const float*)d_in[11];
    const float* bhh1f = (const float*)d_in[12];
    const float* Wih1b = (const float*)d_in[13];
    const float* bih1b = (const float*)d_in[15];
    const float* bhh1b = (const float*)d_in[16];
    const float* fcw   = (const float*)d_in[17];
    const float* fcb   = (const float*)d_in[18];

    char* ws = (char*)d_ws;
    _Float16* out0 = (_Float16*)(ws + O_OUT0);
    _Float16* xw1  = (_Float16*)(ws + O_XW1);
    _Float16* x16  = (_Float16*)(ws + O_X16);
    __half2*  wp   = (__half2*)(ws + O_WP);
    float*    h1f  = (float*)(ws + O_H1F);
    _Float16* wf16 = (_Float16*)(ws + O_WF16);
    float*    out  = (float*)d_out;

    prep<<<4336, 256, 0, stream>>>(x, x16, Wih1f, wf16, Wih1b, wp);

    scan_l0<<<dim3(16, 2), 768, 0, stream>>>(x16, Wih0f, Whh0f, bih0f, bhh0f,
                                             Wih0b, Whh0b, bih0b, bhh0b, out0);

    gemm_xw1<<<2048, 256, 0, stream>>>(out0, wf16, bih1f, xw1);

    scan_l1<<<16, 768, 0, stream>>>(xw1, Whh1f, bhh1f, h1f);

    final_k<<<256, 384, 0, stream>>>(out0, h1f, wp, bih1b, bhh1b, fcw, fcb, out);
}